// Round 7
// baseline (315.703 us; speedup 1.0000x reference)
//
#include <hip/hip_runtime.h>
#include <math.h>

#define BB 32
#define LL 128
#define HH 512
#define MM 512
#define NM 544          // 32 x-matrices + 512 centroids
#define EPSF 1e-8f
#define CPLEN 10240     // 10 upper 32x32 tiles * 1024 floats (offdiag pre-scaled by sqrt2)
#define NCH 40          // k-chunks of 256 floats

typedef __attribute__((ext_vector_type(8))) short short8b;   // 8 bf16
typedef __attribute__((ext_vector_type(4))) float f32x4;
typedef __attribute__((ext_vector_type(16))) float f32x16;

// ---------------- ws layout (floats) ----------------
//   Cp     [544][10240]   @ 0
//   part   [40][32][512]  @ 5570560
//   normsq [544]          @ 6225920
//   hsic   [32][512]      @ 6226464
//   ids    [32] (int)     @ 6242848
#define NWS_CP    0
#define NWS_PART  5570560
#define NWS_NSQ   6225920
#define NWS_HSIC  6226464
#define NWS_IDS   6242848

__device__ __constant__ int TI_[10] = {0,0,0,0,1,1,1,2,2,3};
__device__ __constant__ int TJ_[10] = {0,1,2,3,1,2,3,2,3,3};

__device__ __forceinline__ unsigned pack2(unsigned lo, unsigned hi) {
    return (lo >> 16) | (hi & 0xffff0000u);
}

// exact 3-plane bf16 split of 8 floats (c = p0+p1+p2 to ~2^-24 rel)
__device__ __forceinline__ void split3(const float4 lo, const float4 hi,
                                       uint4& p0, uint4& p1, uint4& p2) {
    float c[8] = {lo.x, lo.y, lo.z, lo.w, hi.x, hi.y, hi.z, hi.w};
    unsigned h[8], m[8], l[8];
#pragma unroll
    for (int i = 0; i < 8; ++i) {
        h[i] = __float_as_uint(c[i]) & 0xffff0000u;
        const float r1 = c[i] - __uint_as_float(h[i]);
        m[i] = __float_as_uint(r1) & 0xffff0000u;
        l[i] = __float_as_uint(r1 - __uint_as_float(m[i]));
    }
    p0 = make_uint4(pack2(h[0],h[1]), pack2(h[2],h[3]), pack2(h[4],h[5]), pack2(h[6],h[7]));
    p1 = make_uint4(pack2(m[0],m[1]), pack2(m[2],m[3]), pack2(m[4],m[5]), pack2(m[6],m[7]));
    p2 = make_uint4(pack2(l[0],l[1]), pack2(l[2],l[3]), pack2(l[4],l[5]), pack2(l[6],l[7]));
}

__device__ __forceinline__ float redxor5(float v) {
    v += __shfl_xor(v, 1, 64);
    v += __shfl_xor(v, 2, 64);
    v += __shfl_xor(v, 4, 64);
    v += __shfl_xor(v, 8, 64);
    v += __shfl_xor(v, 16, 64);
    return v;
}

// load 4 strips' fragment floats for k-step t: 2 float4 per strip
#define LOADV(dst, t) do {                                                  \
    _Pragma("unroll")                                                       \
    for (int p_ = 0; p_ < 4; ++p_) {                                        \
        const float* rp_ = Abase[p_] + (t) * 16;                            \
        dst[2*p_]   = *(const float4*)rp_;                                  \
        dst[2*p_+1] = *(const float4*)(rp_ + 4);                            \
    } } while (0)

#define SPLIT4(src, fr) do {                                                \
    _Pragma("unroll")                                                       \
    for (int p_ = 0; p_ < 4; ++p_) {                                        \
        uint4 u0_, u1_, u2_;                                                \
        split3(src[2*p_], src[2*p_+1], u0_, u1_, u2_);                      \
        fr[p_][0] = *(short8b*)&u0_;                                        \
        fr[p_][1] = *(short8b*)&u1_;                                        \
        fr[p_][2] = *(short8b*)&u2_;                                        \
    } } while (0)

#define MFMA60(fr) do {                                                     \
    const int PA_[6] = {0,0,1,1,0,2};                                       \
    const int PB_[6] = {0,1,0,1,2,0};                                       \
    _Pragma("unroll")                                                       \
    for (int ps_ = 0; ps_ < 6; ++ps_) {                                     \
        _Pragma("unroll")                                                   \
        for (int g_ = 0; g_ < 10; ++g_)                                     \
            acc[g_] = __builtin_amdgcn_mfma_f32_32x32x16_bf16(              \
                fr[TI_[g_]][PA_[ps_]], fr[TJ_[g_]][PB_[ps_]], acc[g_], 0, 0, 0); \
    } } while (0)

// =====================================================================
// K1: one wave computes one full centered Gram. 544 blocks x 64 threads.
// Fragments loaded straight from global in MFMA layout (lane -> row
// lane&31 of strip, k-octet lane>>5). No LDS / barriers in main loop.
// =====================================================================
__global__ __launch_bounds__(64, 1)
void gram_wave(const float* __restrict__ x,
               const float* __restrict__ cent,
               float* __restrict__ Cp,
               float* __restrict__ normsq)
{
    __shared__ __align__(16) float rowacc[128];   // wave-private, 512 B

    const int lane = threadIdx.x;
    const int r32  = lane & 31;
    const int oct  = lane >> 5;
    const int n    = blockIdx.x;
    const float* Amat = (n < BB) ? (x + (size_t)n * LL * HH)
                                 : (cent + (size_t)(n - BB) * LL * HH);
    const float* Abase[4];
#pragma unroll
    for (int p = 0; p < 4; ++p)
        Abase[p] = Amat + (size_t)(32 * p + r32) * HH + oct * 8;

    f32x16 acc[10];
#pragma unroll
    for (int g = 0; g < 10; ++g)
#pragma unroll
        for (int q = 0; q < 16; ++q) acc[g][q] = 0.f;

    float4 sA[8], sB[8];
    short8b frA[4][3], frB[4][3];

    LOADV(sA, 0);
    LOADV(sB, 1);
#pragma unroll 1
    for (int tt = 0; tt < 16; ++tt) {
        SPLIT4(sA, frA);
        if (tt < 15) { LOADV(sA, 2 * tt + 2); }
        MFMA60(frA);
        SPLIT4(sB, frB);
        if (tt < 15) { LOADV(sB, 2 * tt + 3); }
        MFMA60(frB);
    }

    // ---- row sums of raw G per strip (reduce over cols = lanes&31) ----
#pragma unroll
    for (int i = 0; i < 4; ++i) {
        float rp[16];
#pragma unroll
        for (int q = 0; q < 16; ++q) {
            float s = 0.f;
#pragma unroll
            for (int g = 0; g < 10; ++g)
                if (TI_[g] == i) s += acc[g][q];
            rp[q] = redxor5(s);
        }
        if (r32 == 0) {
#pragma unroll
            for (int q = 0; q < 16; ++q)
                rowacc[i * 32 + (q & 3) + 8 * (q >> 2) + 4 * oct] = rp[q];
        }
    }
    // ---- transposed (col-sum) contributions from offdiag tiles ----
    {
        float cs1 = 0.f, cs2 = 0.f, cs3 = 0.f;
#pragma unroll
        for (int g = 0; g < 10; ++g) {
            if (TI_[g] == TJ_[g]) continue;
            float cp = 0.f;
#pragma unroll
            for (int q = 0; q < 16; ++q) cp += acc[g][q];
            if (TJ_[g] == 1) cs1 += cp;
            else if (TJ_[g] == 2) cs2 += cp;
            else cs3 += cp;
        }
        cs1 += __shfl_xor(cs1, 32, 64);
        cs2 += __shfl_xor(cs2, 32, 64);
        cs3 += __shfl_xor(cs3, 32, 64);
        if (oct == 0) {
            rowacc[1 * 32 + r32] += cs1;
            rowacc[2 * 32 + r32] += cs2;
            rowacc[3 * 32 + r32] += cs3;
        }
    }

    // ---- grand mean ----
    float tot = rowacc[lane] + rowacc[lane + 64];
    tot += __shfl_xor(tot, 1, 64);
    tot += __shfl_xor(tot, 2, 64);
    tot += __shfl_xor(tot, 4, 64);
    tot += __shfl_xor(tot, 8, 64);
    tot += __shfl_xor(tot, 16, 64);
    tot += __shfl_xor(tot, 32, 64);
    const float gm = tot * (1.f / 16384.f);

    // ---- per-strip row-mean fragments this lane needs ----
    f32x4 rim[4][4];   // [strip][c-quad] for rows 8c+4*oct .. +3
#pragma unroll
    for (int i = 0; i < 4; ++i)
#pragma unroll
        for (int c = 0; c < 4; ++c) {
            const f32x4 rv = *(const f32x4*)&rowacc[i * 32 + 8 * c + 4 * oct];
            rim[i][c][0] = gm - rv[0] * (1.f / 128.f);
            rim[i][c][1] = gm - rv[1] * (1.f / 128.f);
            rim[i][c][2] = gm - rv[2] * (1.f / 128.f);
            rim[i][c][3] = gm - rv[3] * (1.f / 128.f);
        }
    float cjs[4];
#pragma unroll
    for (int j = 0; j < 4; ++j) cjs[j] = rowacc[j * 32 + r32] * (1.f / 128.f);

    // ---- center + sqrt2-scale offdiag + store + ||C||^2 ----
    float nsq = 0.f;
    float* dstn = Cp + (size_t)n * CPLEN;
#pragma unroll
    for (int g = 0; g < 10; ++g) {
        const int i = TI_[g], j = TJ_[g];
        const float sc = (i == j) ? 1.f : 1.41421356237309505f;
        const float cj = cjs[j];
#pragma unroll
        for (int c = 0; c < 4; ++c) {
            f32x4 o;
#pragma unroll
            for (int q = 0; q < 4; ++q) {
                const float val = (acc[g][c * 4 + q] + rim[i][c][q] - cj) * sc;
                nsq = fmaf(val, val, nsq);
                o[q] = val;
            }
            *(f32x4*)(dstn + g * 1024 + (c * 2 + oct) * 128 + r32 * 4) = o;
        }
    }
    nsq += __shfl_xor(nsq, 1, 64);
    nsq += __shfl_xor(nsq, 2, 64);
    nsq += __shfl_xor(nsq, 4, 64);
    nsq += __shfl_xor(nsq, 8, 64);
    nsq += __shfl_xor(nsq, 16, 64);
    nsq += __shfl_xor(nsq, 32, 64);
    if (lane == 0) normsq[n] = nsq;
}

// =====================================================================
// K2: hsic partials. grid = 16 m-tiles x 40 k-chunks (640 blocks).
// =====================================================================
__global__ __launch_bounds__(256, 2)
void hsic_partial(const float* __restrict__ Cp, float* __restrict__ part)
{
    __shared__ float cx[32][260];
    __shared__ float red2[256][16];

    const int tid = threadIdx.x;
    const int bx  = blockIdx.x;
    const int mt  = bx / NCH;
    const int kc  = bx % NCH;
    const int k0  = kc * 256;

#pragma unroll
    for (int i = 0; i < 8; ++i) {
        const int idx = i * 1024 + tid * 4;
        const int b = idx >> 8, k = idx & 255;
        *(float4*)&cx[b][k] = *(const float4*)&Cp[(size_t)b * CPLEN + k0 + k];
    }
    __syncthreads();

    const int kq = tid >> 6;
    const int bg = (tid >> 3) & 7;
    const int mg = tid & 7;
    const float* cyBase = Cp + (size_t)(BB + mt * 32 + mg * 4) * CPLEN + k0 + kq * 64;

    float a[4][4];
#pragma unroll
    for (int bi = 0; bi < 4; ++bi)
#pragma unroll
        for (int mi = 0; mi < 4; ++mi) a[bi][mi] = 0.f;

    for (int kk = 0; kk < 16; ++kk) {
        float4 cy[4];
#pragma unroll
        for (int mi = 0; mi < 4; ++mi)
            cy[mi] = *(const float4*)(cyBase + (size_t)mi * CPLEN + kk * 4);
        float4 cxv[4];
#pragma unroll
        for (int bi = 0; bi < 4; ++bi)
            cxv[bi] = *(const float4*)&cx[bg + bi * 8][kq * 64 + kk * 4];
#pragma unroll
        for (int bi = 0; bi < 4; ++bi)
#pragma unroll
            for (int mi = 0; mi < 4; ++mi) {
                a[bi][mi] = fmaf(cxv[bi].x, cy[mi].x, a[bi][mi]);
                a[bi][mi] = fmaf(cxv[bi].y, cy[mi].y, a[bi][mi]);
                a[bi][mi] = fmaf(cxv[bi].z, cy[mi].z, a[bi][mi]);
                a[bi][mi] = fmaf(cxv[bi].w, cy[mi].w, a[bi][mi]);
            }
    }

#pragma unroll
    for (int e = 0; e < 16; ++e) red2[tid][e] = a[e >> 2][e & 3];
    __syncthreads();
    if (tid < 64) {
#pragma unroll
        for (int e = 0; e < 16; ++e) {
            const float s = red2[tid][e] + red2[tid + 64][e] +
                            red2[tid + 128][e] + red2[tid + 192][e];
            const int bi = e >> 2, mi = e & 3;
            const int b = ((tid >> 3) & 7) + bi * 8;
            const int m = mt * 32 + (tid & 7) * 4 + mi;
            part[((size_t)kc * 32 + b) * 512 + m] = s;
        }
    }
}

// =====================================================================
// K3: combine partials, loss matrix + per-row argmax (first occurrence)
// =====================================================================
__global__ __launch_bounds__(256)
void combine_loss(const float* __restrict__ part,
                  const float* __restrict__ normsq,
                  float* __restrict__ hsic,
                  int* __restrict__ ids,
                  float* __restrict__ out)
{
    __shared__ float rv[256];
    __shared__ int   ri[256];
    const int b = blockIdx.x;
    const int tid = threadIdx.x;
    const float vx = sqrtf(normsq[b]);

    float best = -INFINITY; int bm = 0;
    for (int m = tid; m < MM; m += 256) {
        float s = 0.f;
        for (int kc = 0; kc < NCH; ++kc)
            s += part[((size_t)kc * 32 + b) * 512 + m];
        hsic[b * MM + m] = s;
        const float vy = sqrtf(normsq[BB + m]);
        const float loss = -logf(fabsf(s) / (vx * vy) + EPSF);
        out[1 + b * MM + m] = loss;
        if (loss > best) { best = loss; bm = m; }   // ascending m keeps earliest
    }
    rv[tid] = best; ri[tid] = bm;
    __syncthreads();
    for (int s2 = 128; s2 > 0; s2 >>= 1) {
        if (tid < s2) {
            if (rv[tid + s2] > rv[tid] ||
                (rv[tid + s2] == rv[tid] && ri[tid + s2] < ri[tid])) {
                rv[tid] = rv[tid + s2]; ri[tid] = ri[tid + s2];
            }
        }
        __syncthreads();
    }
    if (tid == 0) { ids[b] = ri[0]; out[1 + BB * MM + b] = (float)ri[0]; }
}

// =====================================================================
// K4: scalar loss via gather identity hsic2[b,c] = hsic[b, idx[c]]
// =====================================================================
__global__ __launch_bounds__(1024)
void scalar_loss(const float* __restrict__ hsic,
                 const float* __restrict__ normsq,
                 const int* __restrict__ ids,
                 float* __restrict__ out)
{
    __shared__ float red[1024];
    const int tid = threadIdx.x;
    const int b = tid >> 5, c = tid & 31;
    const int m = ids[c];
    red[tid] = fabsf(hsic[b * MM + m]) /
               (sqrtf(normsq[b]) * sqrtf(normsq[BB + m]));
    __syncthreads();
    for (int s = 512; s > 0; s >>= 1) {
        if (tid < s) red[tid] += red[tid + s];
        __syncthreads();
    }
    if (tid == 0) out[0] = -logf(red[0] * (1.f / 1024.f) + EPSF);
}

// =====================================================================
extern "C" void kernel_launch(void* const* d_in, const int* in_sizes, int n_in,
                              void* d_out, int out_size, void* d_ws, size_t ws_size,
                              hipStream_t stream) {
    const float* x    = (const float*)d_in[0];   // (32,128,512)
    const float* cent = (const float*)d_in[1];   // (512, 128*512)
    float* out = (float*)d_out;
    float* ws  = (float*)d_ws;

    float* Cp     = ws + NWS_CP;
    float* part   = ws + NWS_PART;
    float* normsq = ws + NWS_NSQ;
    float* hsic   = ws + NWS_HSIC;
    int*   ids    = (int*)(ws + NWS_IDS);

    gram_wave<<<NM, 64, 0, stream>>>(x, cent, Cp, normsq);
    hsic_partial<<<16 * NCH, 256, 0, stream>>>(Cp, part);
    combine_loss<<<BB, 256, 0, stream>>>(part, normsq, hsic, ids, out);
    scalar_loss<<<1, 1024, 0, stream>>>(hsic, normsq, ids, out);
}

// Round 8
// 96.389 us; speedup vs baseline: 3.2753x; 3.2753x over previous
//
#include <hip/hip_runtime.h>
#include <math.h>

#define BB 32
#define LL 128
#define HH 512
#define MM 512
#define NM 544          // 32 x-matrices + 512 centroids
#define EPSF 1e-8f
#define CPLEN 10240     // 10 upper 32x32 tiles * 1024 floats (offdiag pre-scaled by sqrt2)
#define NCH 40          // k-chunks of 256 floats

typedef __attribute__((ext_vector_type(8))) short short8b;   // 8 bf16
typedef __attribute__((ext_vector_type(4))) float f32x4;
typedef __attribute__((ext_vector_type(16))) float f32x16;

// ---------------- ws layout (floats) ----------------
//   Cp     [544][10240]   @ 0
//   part   [40][32][512]  @ 5570560
//   normsq [544]          @ 6225920
//   hsic   [32][512]      @ 6226464
//   ids    [32] (int)     @ 6242848
#define NWS_CP    0
#define NWS_PART  5570560
#define NWS_NSQ   6225920
#define NWS_HSIC  6226464
#define NWS_IDS   6242848

__device__ __forceinline__ unsigned pack2(unsigned lo, unsigned hi) {
    return (lo >> 16) | (hi & 0xffff0000u);
}

// exact 3-plane bf16 split of 8 floats (c = p0+p1+p2 to ~2^-24 rel)
__device__ __forceinline__ void split3(const float4 lo, const float4 hi,
                                       uint4& p0, uint4& p1, uint4& p2) {
    float c[8] = {lo.x, lo.y, lo.z, lo.w, hi.x, hi.y, hi.z, hi.w};
    unsigned h[8], m[8], l[8];
#pragma unroll
    for (int i = 0; i < 8; ++i) {
        h[i] = __float_as_uint(c[i]) & 0xffff0000u;
        const float r1 = c[i] - __uint_as_float(h[i]);
        m[i] = __float_as_uint(r1) & 0xffff0000u;
        l[i] = __float_as_uint(r1 - __uint_as_float(m[i]));
    }
    p0 = make_uint4(pack2(h[0],h[1]), pack2(h[2],h[3]), pack2(h[4],h[5]), pack2(h[6],h[7]));
    p1 = make_uint4(pack2(m[0],m[1]), pack2(m[2],m[3]), pack2(m[4],m[5]), pack2(m[6],m[7]));
    p2 = make_uint4(pack2(l[0],l[1]), pack2(l[2],l[3]), pack2(l[4],l[5]), pack2(l[6],l[7]));
}

// 6 significant plane-products: hh, hm, mh, mm, hl, lh
__device__ __forceinline__ void mfma6(f32x16& d, const short8b a[3], const short8b b[3]) {
    d = __builtin_amdgcn_mfma_f32_32x32x16_bf16(a[0], b[0], d, 0, 0, 0);
    d = __builtin_amdgcn_mfma_f32_32x32x16_bf16(a[0], b[1], d, 0, 0, 0);
    d = __builtin_amdgcn_mfma_f32_32x32x16_bf16(a[1], b[0], d, 0, 0, 0);
    d = __builtin_amdgcn_mfma_f32_32x32x16_bf16(a[1], b[1], d, 0, 0, 0);
    d = __builtin_amdgcn_mfma_f32_32x32x16_bf16(a[0], b[2], d, 0, 0, 0);
    d = __builtin_amdgcn_mfma_f32_32x32x16_bf16(a[2], b[0], d, 0, 0, 0);
}

// fragment load: lane -> row strip*32+(lane&31), k-octet lane>>5
__device__ __forceinline__ void ldstrip(const uint4* P, int strip, int lane, short8b f[3]) {
    const int s = lane >> 5;
    const int r = strip * 32 + (lane & 31);
#pragma unroll
    for (int p = 0; p < 3; ++p) {
        uint4 u = P[(p * 2 + s) * 128 + r];
        f[p] = *(const short8b*)&u;
    }
}

// flat index of G[a][b] inside a 32x32 tile (verified 32x32 C/D layout:
// col=lane&31, row=(reg&3)+8*(reg>>2)+4*(lane>>5)); reg-quad c stored at
// (c*2+hi)*128 + col*4 + q.
__device__ __forceinline__ int flatAB(int a, int b) {
    return ((a >> 3) * 2 + ((a >> 2) & 1)) * 128 + b * 4 + (a & 3);
}
// upper-tile slot for i<=j: (0,0)=0,(0,1)=1,(0,2)=2,(0,3)=3,(1,1)=4,...
__device__ __forceinline__ int Tix(int i, int j) {
    return i * (7 - i) / 2 + j;
}

// write or accumulate one 32x32 tile into LDS buf
__device__ __forceinline__ void put_tile(float* buf, int slot, const f32x16& a,
                                         int lane, bool add) {
    const int hi = lane >> 5, col = lane & 31;
#pragma unroll
    for (int c = 0; c < 4; ++c) {
        const int idx = slot * 1024 + (c * 2 + hi) * 128 + col * 4;
        f32x4 v;
        v[0] = a[c * 4 + 0]; v[1] = a[c * 4 + 1];
        v[2] = a[c * 4 + 2]; v[3] = a[c * 4 + 3];
        if (add) {
            const f32x4 o = *(const f32x4*)&buf[idx];
            v[0] += o[0]; v[1] += o[1]; v[2] += o[2]; v[3] += o[3];
        }
        *(f32x4*)&buf[idx] = v;
    }
}

// =====================================================================
// K1: centered Gram, 544 blocks x 512 threads (8 waves).
// Waves 0-3: k in [0,256); waves 4-7: k in [256,512). Each group double-
// buffers its own 24 KB stage slice; 2-deep register prefetch; one
// __syncthreads per k-step. Epilogue: group-partial reduce in LDS,
// double-center, sqrt2-scale offdiag, store upper triangle + ||C||^2.
// =====================================================================
__global__ __launch_bounds__(512, 4)
void gram8(const float* __restrict__ x,
           const float* __restrict__ cent,
           float* __restrict__ Cp,
           float* __restrict__ normsq)
{
    __shared__ __align__(16) unsigned char smraw[49152];  // stage / buf union
    __shared__ float rmv[128];
    __shared__ float red[512];
    __shared__ float gmsh;

    uint4* stage = (uint4*)smraw;   // [g]:1536 + [pb]:768 + (pl*2+oct)*128 + row
    float* buf   = (float*)smraw;   // epilogue: 10 tiles x 1024 floats

    const int tid  = threadIdx.x;
    const int lane = tid & 63;
    const int wid  = tid >> 6;      // 0..7
    const int g    = wid >> 2;      // k-group
    const int gw   = wid & 3;       // wave within group
    const int n    = blockIdx.x;
    const float* Amat = (n < BB) ? (x + (size_t)n * LL * HH)
                                 : (cent + (size_t)(n - BB) * LL * HH);

    const int trow  = (tid >> 1) & 127;  // staging row
    const int shalf = tid & 1;           // k-octet within k16
    const float* rowp = Amat + (size_t)trow * HH + g * 256 + shalf * 8;

    f32x16 a0, a1, a2;
#pragma unroll
    for (int q = 0; q < 16; ++q) { a0[q] = 0.f; a1[q] = 0.f; a2[q] = 0.f; }

    // 2-deep prefetch
    float4 vA0 = *(const float4*)(rowp);
    float4 vA1 = *(const float4*)(rowp + 4);
    float4 vB0 = *(const float4*)(rowp + 16);
    float4 vB1 = *(const float4*)(rowp + 20);

#pragma unroll 2
    for (int t = 0; t < 16; ++t) {
        const int pb = t & 1;
        uint4 p0, p1, p2;
        if (pb == 0) split3(vA0, vA1, p0, p1, p2);
        else         split3(vB0, vB1, p0, p1, p2);

        uint4* SW = stage + g * 1536 + pb * 768;
        SW[(0 * 2 + shalf) * 128 + trow] = p0;
        SW[(1 * 2 + shalf) * 128 + trow] = p1;
        SW[(2 * 2 + shalf) * 128 + trow] = p2;

        if (t < 14) {
            const float* np = rowp + (t + 2) * 16;
            if (pb == 0) { vA0 = *(const float4*)np; vA1 = *(const float4*)(np + 4); }
            else         { vB0 = *(const float4*)np; vB1 = *(const float4*)(np + 4); }
        }

        __syncthreads();

        const uint4* Pr = stage + g * 1536 + pb * 768;
        short8b fa[3], fb[3];
        if (gw == 0) {            // (0,3),(1,3),(2,3)
            ldstrip(Pr, 3, lane, fb);
            ldstrip(Pr, 0, lane, fa); mfma6(a0, fa, fb);
            ldstrip(Pr, 1, lane, fa); mfma6(a1, fa, fb);
            ldstrip(Pr, 2, lane, fa); mfma6(a2, fa, fb);
        } else if (gw == 1) {     // (3,3),(0,2),(1,2)
            ldstrip(Pr, 3, lane, fa); mfma6(a0, fa, fa);
            ldstrip(Pr, 2, lane, fb);
            ldstrip(Pr, 0, lane, fa); mfma6(a1, fa, fb);
            ldstrip(Pr, 1, lane, fa); mfma6(a2, fa, fb);
        } else if (gw == 2) {     // (2,2),(0,1)
            ldstrip(Pr, 2, lane, fa); mfma6(a0, fa, fa);
            ldstrip(Pr, 0, lane, fa);
            ldstrip(Pr, 1, lane, fb); mfma6(a1, fa, fb);
        } else {                  // (0,0),(1,1)
            ldstrip(Pr, 0, lane, fa); mfma6(a0, fa, fa);
            ldstrip(Pr, 1, lane, fa); mfma6(a1, fa, fa);
        }
    }

    __syncthreads();   // all MFMA reads done; stage becomes buf

    // ---- combine the two k-group partials in LDS ----
    if (g == 0) {
        if (gw == 0)      { put_tile(buf, 3, a0, lane, false); put_tile(buf, 6, a1, lane, false); put_tile(buf, 8, a2, lane, false); }
        else if (gw == 1) { put_tile(buf, 9, a0, lane, false); put_tile(buf, 2, a1, lane, false); put_tile(buf, 5, a2, lane, false); }
        else if (gw == 2) { put_tile(buf, 7, a0, lane, false); put_tile(buf, 1, a1, lane, false); }
        else              { put_tile(buf, 0, a0, lane, false); put_tile(buf, 4, a1, lane, false); }
    }
    __syncthreads();
    if (g == 1) {
        if (gw == 0)      { put_tile(buf, 3, a0, lane, true); put_tile(buf, 6, a1, lane, true); put_tile(buf, 8, a2, lane, true); }
        else if (gw == 1) { put_tile(buf, 9, a0, lane, true); put_tile(buf, 2, a1, lane, true); put_tile(buf, 5, a2, lane, true); }
        else if (gw == 2) { put_tile(buf, 7, a0, lane, true); put_tile(buf, 1, a1, lane, true); }
        else              { put_tile(buf, 0, a0, lane, true); put_tile(buf, 4, a1, lane, true); }
    }
    __syncthreads();

    // ---- row sums of raw G (for double-centering) ----
    float Sv = 0.f;
    if (tid < 128) {
        const int i = tid >> 5, ri = tid & 31;
#pragma unroll
        for (int j = 0; j < 4; ++j) {
            if (j >= i) {
                const int gt = Tix(i, j);
#pragma unroll
                for (int b = 0; b < 32; ++b)
                    Sv += buf[gt * 1024 + flatAB(ri, b)];
            } else {
                const int gt = Tix(j, i);
#pragma unroll
                for (int a = 0; a < 32; ++a)
                    Sv += buf[gt * 1024 + flatAB(a, ri)];
            }
        }
        rmv[tid] = Sv * (1.f / 128.f);
    }
    red[tid] = (tid < 128) ? Sv : 0.f;
    __syncthreads();
    for (int s2 = 256; s2 > 0; s2 >>= 1) {
        if (tid < s2) red[tid] += red[tid + s2];
        __syncthreads();
    }
    if (tid == 0) gmsh = red[0] * (1.f / 16384.f);
    __syncthreads();
    const float gm = gmsh;

    // ---- center + sqrt2-scale offdiag + store + ||C||^2 ----
    float nsq = 0.f;
    float* dstn = Cp + (size_t)n * CPLEN;
#pragma unroll
    for (int u5 = 0; u5 < 5; ++u5) {
        const int u  = u5 * 512 + tid;        // f32x4 index 0..2559
        const int gt = u >> 8;                // tile slot 0..9
        const int fo = (u & 255) * 4;         // float offset in tile
        const int c2 = fo >> 7;
        const int col = (fo >> 2) & 31;
        const int ar = (c2 >> 1) * 8 + (c2 & 1) * 4;
        int i, j;
        if (gt < 4)      { i = 0; j = gt; }
        else if (gt < 7) { i = 1; j = gt - 3; }
        else if (gt < 9) { i = 2; j = gt - 5; }
        else             { i = 3; j = 3; }
        const float sc = (i == j) ? 1.f : 1.41421356237309505f;
        const f32x4 vv = *(const f32x4*)&buf[u * 4];
        const float cj = rmv[j * 32 + col];
        f32x4 o;
#pragma unroll
        for (int q = 0; q < 4; ++q) {
            const float val = (vv[q] + gm - rmv[i * 32 + ar + q] - cj) * sc;
            nsq = fmaf(val, val, nsq);
            o[q] = val;
        }
        *(f32x4*)(dstn + u * 4) = o;
    }
    __syncthreads();
    red[tid] = nsq;
    __syncthreads();
    for (int s2 = 256; s2 > 0; s2 >>= 1) {
        if (tid < s2) red[tid] += red[tid + s2];
        __syncthreads();
    }
    if (tid == 0) normsq[n] = red[0];
}

// =====================================================================
// K2: hsic partials. grid = 16 m-tiles x 40 k-chunks (640 blocks).
// =====================================================================
__global__ __launch_bounds__(256, 2)
void hsic_partial(const float* __restrict__ Cp, float* __restrict__ part)
{
    __shared__ float cx[32][260];
    __shared__ float red2[256][16];

    const int tid = threadIdx.x;
    const int bx  = blockIdx.x;
    const int mt  = bx / NCH;
    const int kc  = bx % NCH;
    const int k0  = kc * 256;

#pragma unroll
    for (int i = 0; i < 8; ++i) {
        const int idx = i * 1024 + tid * 4;
        const int b = idx >> 8, k = idx & 255;
        *(float4*)&cx[b][k] = *(const float4*)&Cp[(size_t)b * CPLEN + k0 + k];
    }
    __syncthreads();

    const int kq = tid >> 6;
    const int bg = (tid >> 3) & 7;
    const int mg = tid & 7;
    const float* cyBase = Cp + (size_t)(BB + mt * 32 + mg * 4) * CPLEN + k0 + kq * 64;

    float a[4][4];
#pragma unroll
    for (int bi = 0; bi < 4; ++bi)
#pragma unroll
        for (int mi = 0; mi < 4; ++mi) a[bi][mi] = 0.f;

    for (int kk = 0; kk < 16; ++kk) {
        float4 cy[4];
#pragma unroll
        for (int mi = 0; mi < 4; ++mi)
            cy[mi] = *(const float4*)(cyBase + (size_t)mi * CPLEN + kk * 4);
        float4 cxv[4];
#pragma unroll
        for (int bi = 0; bi < 4; ++bi)
            cxv[bi] = *(const float4*)&cx[bg + bi * 8][kq * 64 + kk * 4];
#pragma unroll
        for (int bi = 0; bi < 4; ++bi)
#pragma unroll
            for (int mi = 0; mi < 4; ++mi) {
                a[bi][mi] = fmaf(cxv[bi].x, cy[mi].x, a[bi][mi]);
                a[bi][mi] = fmaf(cxv[bi].y, cy[mi].y, a[bi][mi]);
                a[bi][mi] = fmaf(cxv[bi].z, cy[mi].z, a[bi][mi]);
                a[bi][mi] = fmaf(cxv[bi].w, cy[mi].w, a[bi][mi]);
            }
    }

#pragma unroll
    for (int e = 0; e < 16; ++e) red2[tid][e] = a[e >> 2][e & 3];
    __syncthreads();
    if (tid < 64) {
#pragma unroll
        for (int e = 0; e < 16; ++e) {
            const float s = red2[tid][e] + red2[tid + 64][e] +
                            red2[tid + 128][e] + red2[tid + 192][e];
            const int bi = e >> 2, mi = e & 3;
            const int b = ((tid >> 3) & 7) + bi * 8;
            const int m = mt * 32 + (tid & 7) * 4 + mi;
            part[((size_t)kc * 32 + b) * 512 + m] = s;
        }
    }
}

// =====================================================================
// K3: combine partials, loss matrix + per-row argmax (first occurrence)
// =====================================================================
__global__ __launch_bounds__(256)
void combine_loss(const float* __restrict__ part,
                  const float* __restrict__ normsq,
                  float* __restrict__ hsic,
                  int* __restrict__ ids,
                  float* __restrict__ out)
{
    __shared__ float rv[256];
    __shared__ int   ri[256];
    const int b = blockIdx.x;
    const int tid = threadIdx.x;
    const float vx = sqrtf(normsq[b]);

    float best = -INFINITY; int bm = 0;
    for (int m = tid; m < MM; m += 256) {
        float s = 0.f;
        for (int kc = 0; kc < NCH; ++kc)
            s += part[((size_t)kc * 32 + b) * 512 + m];
        hsic[b * MM + m] = s;
        const float vy = sqrtf(normsq[BB + m]);
        const float loss = -logf(fabsf(s) / (vx * vy) + EPSF);
        out[1 + b * MM + m] = loss;
        if (loss > best) { best = loss; bm = m; }   // ascending m keeps earliest
    }
    rv[tid] = best; ri[tid] = bm;
    __syncthreads();
    for (int s2 = 128; s2 > 0; s2 >>= 1) {
        if (tid < s2) {
            if (rv[tid + s2] > rv[tid] ||
                (rv[tid + s2] == rv[tid] && ri[tid + s2] < ri[tid])) {
                rv[tid] = rv[tid + s2]; ri[tid] = ri[tid + s2];
            }
        }
        __syncthreads();
    }
    if (tid == 0) { ids[b] = ri[0]; out[1 + BB * MM + b] = (float)ri[0]; }
}

// =====================================================================
// K4: scalar loss via gather identity hsic2[b,c] = hsic[b, idx[c]]
// =====================================================================
__global__ __launch_bounds__(1024)
void scalar_loss(const float* __restrict__ hsic,
                 const float* __restrict__ normsq,
                 const int* __restrict__ ids,
                 float* __restrict__ out)
{
    __shared__ float red[1024];
    const int tid = threadIdx.x;
    const int b = tid >> 5, c = tid & 31;
    const int m = ids[c];
    red[tid] = fabsf(hsic[b * MM + m]) /
               (sqrtf(normsq[b]) * sqrtf(normsq[BB + m]));
    __syncthreads();
    for (int s = 512; s > 0; s >>= 1) {
        if (tid < s) red[tid] += red[tid + s];
        __syncthreads();
    }
    if (tid == 0) out[0] = -logf(red[0] * (1.f / 1024.f) + EPSF);
}

// =====================================================================
extern "C" void kernel_launch(void* const* d_in, const int* in_sizes, int n_in,
                              void* d_out, int out_size, void* d_ws, size_t ws_size,
                              hipStream_t stream) {
    const float* x    = (const float*)d_in[0];   // (32,128,512)
    const float* cent = (const float*)d_in[1];   // (512, 128*512)
    float* out = (float*)d_out;
    float* ws  = (float*)d_ws;

    float* Cp     = ws + NWS_CP;
    float* part   = ws + NWS_PART;
    float* normsq = ws + NWS_NSQ;
    float* hsic   = ws + NWS_HSIC;
    int*   ids    = (int*)(ws + NWS_IDS);

    gram8<<<NM, 512, 0, stream>>>(x, cent, Cp, normsq);
    hsic_partial<<<16 * NCH, 256, 0, stream>>>(Cp, part);
    combine_loss<<<BB, 256, 0, stream>>>(part, normsq, hsic, ids, out);
    scalar_loss<<<1, 1024, 0, stream>>>(hsic, normsq, ids, out);
}